// Round 1
// baseline (257.487 us; speedup 1.0000x reference)
//
#include <hip/hip_runtime.h>

// CTC batch cost (keras ctc_batch_cost semantics), forward only.
// B=512, T=512, C=128 (blank = C-1 = 127), L=32, S = 2L+1 = 65.
// One wave (64 lanes) per batch element. Lane s holds alpha[s] for s in [0,63];
// lane 63 additionally carries state 64 (last blank, needs only states 63/64).

#define NEG_INF (-1e30f)
#define EPSF    (1e-7f)

constexpr int T_ = 512;
constexpr int C_ = 128;
constexpr int L_ = 32;
constexpr int PF = 8;   // prefetch depth (loads in flight per wave)

__launch_bounds__(64)
__global__ void ctc_loss_kernel(const int* __restrict__ y_true,
                                const float* __restrict__ y_pred,
                                float* __restrict__ out) {
    const int b    = blockIdx.x;
    const int lane = threadIdx.x;

    const float* base = y_pred + (size_t)b * T_ * C_;
    const int*   lbl  = y_true + b * L_;

    // Extended label class for this lane's state s = lane:
    //   even s -> blank (C-1); odd s -> y_true[b][(s-1)/2]
    const int odd = lane & 1;
    const int cls = odd ? lbl[lane >> 1] : (C_ - 1);

    // skip[s] = s>=2 && ext[s]!=blank && ext[s]!=ext[s-2]
    // Only odd s>=3 can skip; labels are in [0, C-2] so ext[s]!=blank holds.
    bool skip = false;
    if (odd && lane >= 3) skip = (cls != lbl[(lane >> 1) - 1]);

    // t = 0 init: only states 0 and 1 are live.
    float raw0 = base[cls];
    float a    = (lane < 2) ? __logf(raw0 + EPSF) : NEG_INF;
    float a64  = NEG_INF;   // state 64, carried by lane 63

    // Register prefetch pipeline for rows t = 1 .. PF
    float raw[PF];
#pragma unroll
    for (int i = 0; i < PF; ++i) {
        raw[i] = base[(1 + i) * C_ + cls];
    }

    for (int t0 = 1; t0 < T_; t0 += PF) {
#pragma unroll
        for (int j = 0; j < PF; ++j) {
            const int t = t0 + j;
            if (t >= T_) break;            // uniform branch (tail)

            const float lp = __logf(raw[j] + EPSF);
            // issue prefetch for t+PF (clamped; redundant last-row loads are harmless)
            const int tn = t + PF;
            raw[j] = base[((tn < T_) ? tn : (T_ - 1)) * C_ + cls];

            // blank log-prob: lane 62 is even -> holds blank's lp
            const float lp_blank = __shfl(lp, 62);

            float a_prev = __shfl_up(a, 1);
            if (lane == 0) a_prev = NEG_INF;
            float a_sk = __shfl_up(a, 2);
            if (!skip) a_sk = NEG_INF;     // lanes 0..2 have skip=false already

            const float a63_old = a;       // lane 63's pre-update value feeds state 64

            const float m   = fmaxf(fmaxf(a, a_prev), a_sk);
            const float lse = m + __logf(__expf(a - m) + __expf(a_prev - m) + __expf(a_sk - m));
            a = lse + lp;

            // state 64 (blank): stay from a64, advance from old alpha[63]
            const float m2 = fmaxf(a64, a63_old);
            a64 = m2 + __logf(__expf(a64 - m2) + __expf(a63_old - m2)) + lp_blank;
        }
    }

    // log P = logsumexp(alpha_T[S-1], alpha_T[S-2]) = lse(a64, a) at lane 63
    if (lane == 63) {
        const float m  = fmaxf(a64, a);
        const float ll = m + __logf(__expf(a64 - m) + __expf(a - m));
        out[b] = -ll;
    }
}

extern "C" void kernel_launch(void* const* d_in, const int* in_sizes, int n_in,
                              void* d_out, int out_size, void* d_ws, size_t ws_size,
                              hipStream_t stream) {
    const int*   y_true = (const int*)d_in[0];
    const float* y_pred = (const float*)d_in[1];
    float*       out    = (float*)d_out;

    const int B = out_size;   // output is [B,1]
    ctc_loss_kernel<<<B, 64, 0, stream>>>(y_true, y_pred, out);
}

// Round 3
// 225.265 us; speedup vs baseline: 1.1430x; 1.1430x over previous
//
#include <hip/hip_runtime.h>

// CTC batch cost (keras ctc_batch_cost semantics), forward only.
// B=512, T=512, C=128 (blank=127), L=32, S=65.
// One wave per batch element; lane s holds alpha[s] (s in 0..63), lane 63
// also carries state 64. Probability domain, 4-row composed updates.
// Numerics: per-group (4-row) rescale by an EXACT power of two derived from
// the exponent of a strided-sampled wave max; integer exponent accumulator.

#define EPSF 1e-7f

constexpr int T_  = 512;
constexpr int C_  = 128;
constexpr int L_  = 32;
constexpr int NG  = 127;  // groups of 4 rows: rows 1..508
constexpr int PFG = 4;    // group prefetch depth (registers)
constexpr int NLD = 17;   // gathered loads per group

__launch_bounds__(64)
__global__ void ctc_loss_kernel(const int* __restrict__ y_true,
                                const float* __restrict__ y_pred,
                                float* __restrict__ out) {
    const int b    = blockIdx.x;
    const int lane = threadIdx.x;

    const float* bb  = y_pred + (size_t)b * T_ * C_;
    const int*   lbl = y_true + b * L_;

    // Static per-lane tables: class and skip-flag for states s-0..s-6, and
    // 0/1 masks for out-of-range shuffle results.
    int   cls[7];
    float sg[7];
#pragma unroll
    for (int i = 0; i < 7; ++i) {
        const int v = lane - i;
        int   c = C_ - 1;     // blank for even / invalid states
        float s = 0.f;
        if (v >= 1 && (v & 1)) {
            c = lbl[(v - 1) >> 1];
            if (v >= 3 && c != lbl[((v - 1) >> 1) - 1]) s = 1.f;
        }
        cls[i] = c;
        sg[i]  = s;
    }
    float msk[9];
#pragma unroll
    for (int i = 0; i < 9; ++i) msk[i] = (lane >= i) ? 1.f : 0.f;

    // t=0 init (prob domain): states 0,1 = q0[cls]+eps, rest 0.
    float a       = (lane < 2) ? (bb[cls[0]] + EPSF) : 0.f;
    float a64     = 0.f;   // state 64, meaningful on lane 63 only
    int   e_total = 0;     // accumulated log2 scale (exact integer)

    // Gather-prefetch: raw probs for 4 groups ahead.
    // Per group (rows t0..t0+3): [0..6]=row t0 cls0..6, [7..11]=row t0+1
    // cls0..4, [12..14]=row t0+2 cls0..2, [15]=row t0+3 cls0, [16]=row t0+3 cls1.
    float Q[PFG][NLD];
    auto loadq = [&](float (&Qk)[NLD], const float* __restrict__ r) {
        Qk[0]  = r[cls[0]];          Qk[1]  = r[cls[1]];
        Qk[2]  = r[cls[2]];          Qk[3]  = r[cls[3]];
        Qk[4]  = r[cls[4]];          Qk[5]  = r[cls[5]];
        Qk[6]  = r[cls[6]];
        Qk[7]  = r[C_ + cls[0]];     Qk[8]  = r[C_ + cls[1]];
        Qk[9]  = r[C_ + cls[2]];     Qk[10] = r[C_ + cls[3]];
        Qk[11] = r[C_ + cls[4]];
        Qk[12] = r[2 * C_ + cls[0]]; Qk[13] = r[2 * C_ + cls[1]];
        Qk[14] = r[2 * C_ + cls[2]];
        Qk[15] = r[3 * C_ + cls[0]]; Qk[16] = r[3 * C_ + cls[1]];
    };
#pragma unroll
    for (int k = 0; k < PFG; ++k) loadq(Q[k], bb + (size_t)(1 + 4 * k) * C_);

    // Strided wave samples of `a` (lanes 3,7,...,63) for the next group's
    // scale. Issued one group early -> DS latency fully hidden.
    float smp[16];
    auto sample = [&]() {
#pragma unroll
        for (int i = 0; i < 16; ++i) smp[i] = __shfl(a, 4 * i + 3);
    };
    sample();

    // Composed 4-step update (linear in alpha -> scaling commutes).
    auto group4 = [&](float (&Qk)[NLD]) {
        float A[9];
        A[0] = a;
#pragma unroll
        for (int i = 1; i <= 8; ++i) A[i] = __shfl_up(a, i) * msk[i];

        float B[7];
#pragma unroll
        for (int i = 0; i <= 6; ++i)
            B[i] = (A[i] + A[i + 1] + sg[i] * A[i + 2]) * (Qk[i] + EPSF);
        float Cc[5];
#pragma unroll
        for (int i = 0; i <= 4; ++i)
            Cc[i] = (B[i] + B[i + 1] + sg[i] * B[i + 2]) * (Qk[7 + i] + EPSF);
        float D[3];
#pragma unroll
        for (int i = 0; i <= 2; ++i)
            D[i] = (Cc[i] + Cc[i + 1] + sg[i] * Cc[i + 2]) * (Qk[12 + i] + EPSF);

        // state-64 chain (valid on lane 63; harmless elsewhere)
        float z = a64;
        z = (z + A[0])  * (Qk[1]  + EPSF);
        z = (z + B[0])  * (Qk[8]  + EPSF);
        z = (z + Cc[0]) * (Qk[13] + EPSF);
        z = (z + D[0])  * (Qk[16] + EPSF);
        a64 = z;

        a = (D[0] + D[1] + sg[0] * D[2]) * (Qk[15] + EPSF);
    };

    // Exact pow2 rescale from the previously-issued samples.
    auto apply_scale = [&]() {
        float t[8];
#pragma unroll
        for (int i = 0; i < 8; ++i) t[i] = fmaxf(smp[i], smp[i + 8]);
#pragma unroll
        for (int i = 0; i < 4; ++i) t[i] = fmaxf(t[i], t[i + 4]);
        float m = fmaxf(fmaxf(t[0], t[1]), fmaxf(t[2], t[3]));
        m = fmaxf(m, 1e-30f);                 // dead-sample guard (self-corrects)
        const unsigned eb = __float_as_uint(m) >> 23;   // biased exponent
        e_total += (int)eb - 127;
        const float inv = __uint_as_float((254u - eb) << 23);  // 2^-e, exact
        a *= inv;
        a64 *= inv;
    };

    // Groups 0..123 with refill; 124..126 consume-only.
    for (int g0 = 0; g0 < 124; g0 += PFG) {
#pragma unroll
        for (int k = 0; k < PFG; ++k) {
            const int g = g0 + k;
            group4(Q[k]);
            apply_scale();
            sample();
            const int gn = g + PFG;
            if (gn < NG) loadq(Q[k], bb + (size_t)(1 + 4 * gn) * C_);
        }
    }

    // Tail-row gathers (rows 509..511) issued before consuming last groups.
    float qo[3], qb[3];
#pragma unroll
    for (int r = 0; r < 3; ++r) {
        const float* rp = bb + (size_t)(509 + r) * C_;
        qo[r] = rp[cls[0]];
        qb[r] = rp[cls[1]];
    }

    group4(Q[0]); apply_scale(); sample();   // group 124
    group4(Q[1]); apply_scale(); sample();   // group 125
    group4(Q[2]); apply_scale();             // group 126 -> alpha after row 508

    // Rows 509..511, single steps (3 rows: no rescale needed).
#pragma unroll
    for (int r = 0; r < 3; ++r) {
        float prev = __shfl_up(a, 1) * msk[1];
        float sk   = __shfl_up(a, 2) * msk[2];
        const float anew = (a + prev + sg[0] * sk) * (qo[r] + EPSF);
        a64 = (a64 + a) * (qb[r] + EPSF);
        a = anew;
    }

    if (lane == 63) {
        out[b] = -(__logf(a + a64) + (float)e_total * 0.6931471805599453f);
    }
}

extern "C" void kernel_launch(void* const* d_in, const int* in_sizes, int n_in,
                              void* d_out, int out_size, void* d_ws, size_t ws_size,
                              hipStream_t stream) {
    const int*   y_true = (const int*)d_in[0];
    const float* y_pred = (const float*)d_in[1];
    float*       out    = (float*)d_out;

    const int B = out_size;   // output is [B,1]
    ctc_loss_kernel<<<B, 64, 0, stream>>>(y_true, y_pred, out);
}